// Round 14
// baseline (123.930 us; speedup 1.0000x reference)
//
#include <hip/hip_runtime.h>
#include <hip/hip_bf16.h>
#include <math.h>

typedef __attribute__((ext_vector_type(8))) short bf16x8;
typedef __attribute__((ext_vector_type(4))) float f32x4;

#define RFEAT 256
#define NBKV 512                        // kv blocks (512 threads, 128 rows each) -> 2 blocks/CU
#define PCOL 66                         // partial cols: 64 v + ksum(64) + 1 pad
#define PARTU (128 * PCOL)              // 8448 u32 per slot (128 feat-pairs x 66 cols)
#define NGRP 8                          // reduceA groups (64 slots each)
#define LDQ 264                         // q_out phi stride (u16): 132%32=4 -> low-conflict

// swizzled LDS offsets (u16 index): stride 128, XOR row bits 3..5 with low feat/col bits
#define PHI_OFF(feat, row) ((feat) * 128 + ((row) ^ (((feat) & 7) << 3)))
#define V_OFF(col, krow)   ((col) * 128 + ((krow) ^ (((col) & 7) << 3)))

// exp2-domain: phi = ratio * exp(x.P'*sc - sc^2*||x||^2/2) = 2^( mfma(x, sc*log2e*P) + rc )
// rc = -0.5*sc^2*log2e*||x||^2 + log2(ratio);  sc = 64^-0.25 = 2^-1.5, ratio = 1/16
#define SCLOG2E 0.51006971688f          // sc * log2(e)
#define RC_COEF -0.09016844006f         // -0.5 * sc^2 * log2(e)
#define LOG2RATIO -4.0f                 // log2(1/16)

__device__ __forceinline__ unsigned short f2bf(float f) {
    union { float f; unsigned int u; } v; v.f = f;
    unsigned int r = v.u + 0x7FFFu + ((v.u >> 16) & 1u);   // RNE
    return (unsigned short)(r >> 16);
}
// HW packed f32->bf16 (RNE) via compiler intrinsic: low16 = bf16(lo), high16 = bf16(hi)
__device__ __forceinline__ unsigned int pack2bf(float lo, float hi) {
    union { __hip_bfloat162 h; unsigned int u; } c;
    c.h = __float22bfloat162_rn(make_float2(lo, hi));
    return c.u;
}
__device__ __forceinline__ float bf2f(unsigned int bits16) {   // low 16 bits -> f32
    union { unsigned int u; float f; } v; v.u = bits16 << 16; return v.f;
}
union bfrag { unsigned int u[4]; bf16x8 v; };

// ---------------- prep_pb: Pb frags (1 block) ----------------
// Pb frag f = kstep*16+nt: element (feat, dim) = SCLOG2E*P[feat][dim],
//   feat = nt*16+(l&15), dim = kstep*32+(l>>4)*8+j.
// Works as B-operand (k=dim, n=feat) AND as A-operand (m=feat, k=dim) — same lane map.
__global__ __launch_bounds__(256)
void prep_pb_kernel(const float* __restrict__ P, unsigned short* __restrict__ Pb)
{
    const int t = threadIdx.x, l = t & 63, g = t >> 6;
    for (int f = g * 8; f < g * 8 + 8; f++) {
        const int kstep = f >> 4, nt = f & 15;
        const float* src = P + (nt * 16 + (l & 15)) * 64 + kstep * 32 + (l >> 4) * 8;
        bfrag fr;
        #pragma unroll
        for (int jp = 0; jp < 4; jp++)
            fr.u[jp] = pack2bf(SCLOG2E * src[2 * jp], SCLOG2E * src[2 * jp + 1]);
        *(bf16x8*)(Pb + f * 512 + l * 8) = fr.v;
    }
}

// ---------------- X row fragments + ssq (shared) ----------------
// Loads row (chunkBase + 16w + (l&15)) elements [(l>>4)*8,+8) and [32+(l>>4)*8,+8);
// builds x0,x1 bf16 frags and the lane-row's rc via in-wave shfl_xor reduction.
__device__ __forceinline__ void phi_xfrag_rcrow(const float* __restrict__ X, int chunkBase,
                                                int l, int w, bfrag& x0f, bfrag& x1f, float& rcrow)
{
    const float4* ar = (const float4*)(X + (size_t)(chunkBase + 16 * w + (l & 15)) * 64 + (l >> 4) * 8);
    float4 x0 = ar[0], x1 = ar[1], x2 = ar[8], x3 = ar[9];
    x0f.u[0] = pack2bf(x0.x, x0.y); x0f.u[1] = pack2bf(x0.z, x0.w);
    x0f.u[2] = pack2bf(x1.x, x1.y); x0f.u[3] = pack2bf(x1.z, x1.w);
    x1f.u[0] = pack2bf(x2.x, x2.y); x1f.u[1] = pack2bf(x2.z, x2.w);
    x1f.u[2] = pack2bf(x3.x, x3.y); x1f.u[3] = pack2bf(x3.z, x3.w);
    // ssq: the 4 lane-groups with equal (l&15) hold disjoint 16-subsets of the row's 64 values
    float ssq = x0.x*x0.x + x0.y*x0.y + x0.z*x0.z + x0.w*x0.w
              + x1.x*x1.x + x1.y*x1.y + x1.z*x1.z + x1.w*x1.w
              + x2.x*x2.x + x2.y*x2.y + x2.z*x2.z + x2.w*x2.w
              + x3.x*x3.x + x3.y*x3.y + x3.z*x3.z + x3.w*x3.w;
    ssq += __shfl_xor(ssq, 16);
    ssq += __shfl_xor(ssq, 32);
    rcrow = RC_COEF * ssq + LOG2RATIO;     // rc of local row (l&15)
}

// ---------------- phi of a 128-row chunk -> swizzled LDS (bf16), 8 waves (kv) ----------------
// D = mfma(X, Pb): m=xrow, n=feat -> thread holds 4 rows x 1 feat -> packed [feat][row] writes.
__device__ __forceinline__ void phi_chunk8_swz(const float* __restrict__ X, int chunkBase,
                                               const unsigned short* __restrict__ Pb,
                                               unsigned short* phi_lds)
{
    const int t = threadIdx.x, l = t & 63, w = t >> 6;
    bfrag x0f, x1f; float rcrow;
    phi_xfrag_rcrow(X, chunkBase, l, w, x0f, x1f, rcrow);
    // redistribute rc to D rows r0..r0+3 (D: col=l&15=feat, row=(l>>4)*4+reg=xrow)
    const int r0 = 4 * (l >> 4);
    float4 rcv;
    rcv.x = __shfl(rcrow, r0 + 0);
    rcv.y = __shfl(rcrow, r0 + 1);
    rcv.z = __shfl(rcrow, r0 + 2);
    rcv.w = __shfl(rcrow, r0 + 3);
    #pragma unroll
    for (int nt = 0; nt < 16; nt++) {
        bf16x8 b0 = *(const bf16x8*)(Pb + nt * 512 + l * 8);
        bf16x8 b1 = *(const bf16x8*)(Pb + (16 + nt) * 512 + l * 8);
        f32x4 acc = (f32x4){rcv.x, rcv.y, rcv.z, rcv.w};   // C-in = rc (free add)
        acc = __builtin_amdgcn_mfma_f32_16x16x32_bf16(x0f.v, b0, acc, 0, 0, 0);
        acc = __builtin_amdgcn_mfma_f32_16x16x32_bf16(x1f.v, b1, acc, 0, 0, 0);
        float p0 = __builtin_amdgcn_exp2f(acc[0]);
        float p1 = __builtin_amdgcn_exp2f(acc[1]);
        float p2 = __builtin_amdgcn_exp2f(acc[2]);
        float p3 = __builtin_amdgcn_exp2f(acc[3]);
        const int col = nt * 16 + (l & 15);   // feature
        const int rr = 16 * w + 4 * (l >> 4); // rows rr..rr+3 (bits 0..2 intact under XOR)
        unsigned int* dst = (unsigned int*)(phi_lds + PHI_OFF(col, rr));
        dst[0] = pack2bf(p0, p1);
        dst[1] = pack2bf(p2, p3);
    }
    __syncthreads();
}

// ---------------- kv: partials[blk] = phi(K)^T @ [V | 1], V staged once in LDS ----------------
__global__ __launch_bounds__(512, 4)
void kv_kernel(const float* __restrict__ Kp, const float* __restrict__ V,
               const unsigned short* __restrict__ Pb, unsigned int* __restrict__ partials)
{
    __shared__ __align__(16) unsigned short phi_lds[RFEAT * 128];   // 64 KB, swizzled
    __shared__ __align__(16) unsigned short v_lds[64 * 128];        // 16 KB, swizzled
    const int t = threadIdx.x, l = t & 63, w = t >> 6;   // w in [0,8)
    const int cb = blockIdx.x * 128;              // one 128-row chunk per block

    // T14 early-issue: thread t loads V col (t&63), krows [(t>>6)*16, +16) -> regs
    const int vcol = t & 63, vr0 = (t >> 6) * 16;
    float vreg[16];
    #pragma unroll
    for (int i = 0; i < 16; i++)
        vreg[i] = V[(size_t)(cb + vr0 + i) * 64 + vcol];

    phi_chunk8_swz(Kp, cb, Pb, phi_lds);          // ends with __syncthreads

    // convert V -> v_lds (bf16, swizzled): 2 x b128 stores per thread
    {
        unsigned int pk[8];
        #pragma unroll
        for (int i = 0; i < 8; i++) pk[i] = pack2bf(vreg[2 * i], vreg[2 * i + 1]);
        unsigned int* d0 = (unsigned int*)(v_lds + V_OFF(vcol, vr0));
        unsigned int* d1 = (unsigned int*)(v_lds + V_OFF(vcol, vr0 + 8));
        d0[0] = pk[0]; d0[1] = pk[1]; d0[2] = pk[2]; d0[3] = pk[3];
        d1[0] = pk[4]; d1[1] = pk[5]; d1[2] = pk[6]; d1[3] = pk[7];
    }
    __syncthreads();

    f32x4 acc[2][5];
    #pragma unroll
    for (int mt = 0; mt < 2; mt++)
        #pragma unroll
        for (int nt = 0; nt < 5; nt++) acc[mt][nt] = (f32x4){0.f, 0.f, 0.f, 0.f};

    bf16x8 ones;   // B-frag for ksum column: B[k][64]=1, rest 0 -> lanes with (l&15)==0
    #pragma unroll
    for (int j = 0; j < 8; j++) ones[j] = (short)(((l & 15) == 0) ? 0x3F80 : 0);

    #pragma unroll
    for (int ks = 0; ks < 4; ks++) {              // 4 k-steps of 32 krows
        const int krow0 = ks * 32 + (l >> 4) * 8;
        bf16x8 af[2];   // A = phi(K)^T: m=feature, k=krow; wave w owns feats [32w,+32)
        #pragma unroll
        for (int mt = 0; mt < 2; mt++)
            af[mt] = *(const bf16x8*)(phi_lds + PHI_OFF(32 * w + mt * 16 + (l & 15), krow0));
        bf16x8 bf4[4];  // B = V bf16 from LDS
        #pragma unroll
        for (int nt = 0; nt < 4; nt++)
            bf4[nt] = *(const bf16x8*)(v_lds + V_OFF(nt * 16 + (l & 15), krow0));
        #pragma unroll
        for (int mt = 0; mt < 2; mt++) {
            #pragma unroll
            for (int nt = 0; nt < 4; nt++)
                acc[mt][nt] = __builtin_amdgcn_mfma_f32_16x16x32_bf16(af[mt], bf4[nt], acc[mt][nt], 0, 0, 0);
            acc[mt][4] = __builtin_amdgcn_mfma_f32_16x16x32_bf16(af[mt], ones, acc[mt][4], 0, 0, 0);
        }
    }
    // partials slot: u32 word at [featpair][col], featpair = feat>>1, stride PCOL
    unsigned int* slot = partials + (size_t)blockIdx.x * PARTU;
    #pragma unroll
    for (int mt = 0; mt < 2; mt++) {
        const int fpb = 16 * w + mt * 8 + ((l >> 4) << 1);   // feat-pair row of regs 0,1
        #pragma unroll
        for (int nt = 0; nt < 5; nt++) {
            if (nt == 4 && (l & 15) != 0) continue;
            const int col = nt * 16 + (l & 15);              // nt==4 -> col 64 (ksum)
            slot[fpb * PCOL + col]       = pack2bf(acc[mt][nt][0], acc[mt][nt][1]);
            slot[(fpb + 1) * PCOL + col] = pack2bf(acc[mt][nt][2], acc[mt][nt][3]);
        }
    }
}

// ---------------- reduceA: sum 64 slots (bf16 pairs, f32 accum) -> p2[g][8448] float2 ----------------
__global__ __launch_bounds__(256)
void reduceA_kernel(const unsigned int* __restrict__ partials, float2* __restrict__ p2)
{
    const int idx = blockIdx.x * 256 + threadIdx.x;   // 33*256 == 8448 exactly
    const int g = blockIdx.y;
    const unsigned int* base = partials + (size_t)g * 64 * PARTU + idx;
    float lo0 = 0.f, hi0 = 0.f, lo1 = 0.f, hi1 = 0.f;
    #pragma unroll 4
    for (int s = 0; s < 64; s += 2) {
        unsigned int u0 = base[(size_t)s * PARTU];
        unsigned int u1 = base[(size_t)(s + 1) * PARTU];
        lo0 += bf2f(u0 & 0xFFFFu); hi0 += bf2f(u0 >> 16);
        lo1 += bf2f(u1 & 0xFFFFu); hi1 += bf2f(u1 >> 16);
    }
    p2[(size_t)g * PARTU + idx] = make_float2(lo0 + lo1, hi0 + hi1);
}

// ---------------- reduceB: sum groups -> Zb (bf16, B-frag octet layout) ----------------
// Zb element (m,n) at ushort ((m>>3)*80 + n)*8 + (m&7); col 64 = ksum.
__global__ __launch_bounds__(256)
void reduceB_kernel(const float2* __restrict__ p2, unsigned short* __restrict__ Zb)
{
    const int idx = blockIdx.x * 256 + threadIdx.x;   // 0..8447
    float sLo = 0.f, sHi = 0.f;
    #pragma unroll
    for (int g = 0; g < NGRP; g++) {
        float2 v = p2[(size_t)g * PARTU + idx];
        sLo += v.x; sHi += v.y;
    }
    const int fp = idx / PCOL, col = idx - fp * PCOL;
    if (col >= 65) return;               // pad col
    const int m0 = 2 * fp, m1 = m0 + 1;
    Zb[((m0 >> 3) * 80 + col) * 8 + (m0 & 7)] = f2bf(sLo);
    Zb[((m1 >> 3) * 80 + col) * 8 + (m1 & 7)] = f2bf(sHi);
}

// ---------------- phi of a 64-row chunk -> LDS [row][feat] (4 waves, for q_out) ----------------
// Swapped operands: D = mfma(Pb, X): m=feat, n=qrow -> thread holds 4 CONSECUTIVE feats
// at one qrow -> 2 packed u32 writes into [row][feat]; C-in = lane's own rcrow (no shfls).
__device__ __forceinline__ void phi_chunk_q(const float* __restrict__ X, int chunkBase,
                                            const unsigned short* __restrict__ Pb,
                                            unsigned short* phi_lds)
{
    const int t = threadIdx.x, l = t & 63, w = t >> 6;
    bfrag x0f, x1f; float rcrow;
    phi_xfrag_rcrow(X, chunkBase, l, w, x0f, x1f, rcrow);
    #pragma unroll
    for (int nt = 0; nt < 16; nt++) {
        bf16x8 b0 = *(const bf16x8*)(Pb + nt * 512 + l * 8);        // A-operand: m=feat
        bf16x8 b1 = *(const bf16x8*)(Pb + (16 + nt) * 512 + l * 8);
        f32x4 acc = (f32x4){rcrow, rcrow, rcrow, rcrow};            // C-in: col=qrow=l&15
        acc = __builtin_amdgcn_mfma_f32_16x16x32_bf16(b0, x0f.v, acc, 0, 0, 0);
        acc = __builtin_amdgcn_mfma_f32_16x16x32_bf16(b1, x1f.v, acc, 0, 0, 0);
        float p0 = __builtin_amdgcn_exp2f(acc[0]);
        float p1 = __builtin_amdgcn_exp2f(acc[1]);
        float p2 = __builtin_amdgcn_exp2f(acc[2]);
        float p3 = __builtin_amdgcn_exp2f(acc[3]);
        // D: col = qrow = l&15; rows = feats nt*16 + (l>>4)*4 + reg (consecutive)
        const int f0 = nt * 16 + (l >> 4) * 4;
        unsigned int* dst = (unsigned int*)(phi_lds + (16 * w + (l & 15)) * LDQ + f0);
        dst[0] = pack2bf(p0, p1);
        dst[1] = pack2bf(p2, p3);
    }
    __syncthreads();
}

// ---------------- q_out: out = normalize( phi(Q) @ Zb ) ----------------
__global__ __launch_bounds__(256, 4)
void q_out_kernel(const float* __restrict__ Q, const unsigned short* __restrict__ Pb,
                  const unsigned short* __restrict__ Zb, float* __restrict__ out)
{
    __shared__ __align__(16) unsigned short phi_lds[64 * LDQ];   // [row][feat], padded
    const int t = threadIdx.x, l = t & 63, w = t >> 6;
    const int base = blockIdx.x * 64;

    phi_chunk_q(Q, base, Pb, phi_lds);

    f32x4 acc[5];
    #pragma unroll
    for (int nt = 0; nt < 5; nt++) acc[nt] = (f32x4){0.f, 0.f, 0.f, 0.f};

    #pragma unroll
    for (int ks = 0; ks < 8; ks++) {
        // A = phi(Q): m = qrow (wave w rows 16w..+16), k = feature
        bf16x8 a = *(const bf16x8*)(phi_lds + (16 * w + (l & 15)) * LDQ + ks * 32 + (l >> 4) * 8);
        #pragma unroll
        for (int nt = 0; nt < 5; nt++) {
            bf16x8 b = *(const bf16x8*)(Zb + ((ks * 4 + (l >> 4)) * 80 + nt * 16 + (l & 15)) * 8);
            acc[nt] = __builtin_amdgcn_mfma_f32_16x16x32_bf16(a, b, acc[nt], 0, 0, 0);
        }
    }
    // denom = output column 64 -> tile 4, lanes with (l&15)==0; broadcast within 16-group
    float inv[4];
    #pragma unroll
    for (int reg = 0; reg < 4; reg++) {
        float den = __shfl(acc[4][reg], (l & 48));
        inv[reg] = 1.0f / den;
    }
    const int row = base + 16 * w + (l >> 4) * 4;
    #pragma unroll
    for (int nt = 0; nt < 4; nt++)
        #pragma unroll
        for (int reg = 0; reg < 4; reg++)
            out[(size_t)(row + reg) * 64 + nt * 16 + (l & 15)] = acc[nt][reg] * inv[reg];
}

extern "C" void kernel_launch(void* const* d_in, const int* in_sizes, int n_in,
                              void* d_out, int out_size, void* d_ws, size_t ws_size,
                              hipStream_t stream) {
    const float* q = (const float*)d_in[0];
    const float* k = (const float*)d_in[1];
    const float* v = (const float*)d_in[2];
    const float* P = (const float*)d_in[3];
    float* out = (float*)d_out;

    unsigned short* Pb = (unsigned short*)d_ws;                      // 32 frags = 32KB
    unsigned short* Zb = Pb + 32 * 512;                              // 20480 u16 = 40KB
    float2* p2 = (float2*)((char*)d_ws + 73728);                     // 8*8448*8 = 540.7KB
    unsigned int* partials = (unsigned int*)((char*)d_ws + 73728 + 540672); // 512*8448*4 = 17.3MB

    prep_pb_kernel<<<1, 256, 0, stream>>>(P, Pb);
    kv_kernel<<<NBKV, 512, 0, stream>>>(k, v, Pb, partials);
    reduceA_kernel<<<dim3(33, NGRP), 256, 0, stream>>>(partials, p2);
    reduceB_kernel<<<33, 256, 0, stream>>>(p2, Zb);
    q_out_kernel<<<1024, 256, 0, stream>>>(q, Pb, Zb, out);
}

// Round 15
// 123.374 us; speedup vs baseline: 1.0045x; 1.0045x over previous
//
#include <hip/hip_runtime.h>
#include <hip/hip_bf16.h>
#include <math.h>

typedef __attribute__((ext_vector_type(8))) short bf16x8;
typedef __attribute__((ext_vector_type(4))) float f32x4;

#define RFEAT 256
#define NBKV 512                        // kv blocks (512 threads, 128 rows each) -> 2 blocks/CU
#define PCOL 66                         // partial cols: 64 v + ksum(64) + 1 pad
#define PARTU (128 * PCOL)              // 8448 u32 per slot (128 feat-pairs x 66 cols)
#define NGRP 8                          // reduceA groups (64 slots each)
#define LDQ 264                         // q_out phi stride (u16): 132%32=4 -> low-conflict

// swizzled LDS offsets (u16 index): stride 128, XOR row bits 3..5 with low feat/col bits
#define PHI_OFF(feat, row) ((feat) * 128 + ((row) ^ (((feat) & 7) << 3)))
#define V_OFF(col, krow)   ((col) * 128 + ((krow) ^ (((col) & 7) << 3)))

// exp2-domain: phi = ratio * exp(x.P'*sc - sc^2*||x||^2/2) = 2^( mfma(x, sc*log2e*P) + rc )
// rc = -0.5*sc^2*log2e*||x||^2 + log2(ratio);  sc = 64^-0.25 = 2^-1.5, ratio = 1/16
#define SCLOG2E 0.51006971688f          // sc * log2(e)
#define RC_COEF -0.09016844006f         // -0.5 * sc^2 * log2(e)
#define LOG2RATIO -4.0f                 // log2(1/16)

__device__ __forceinline__ unsigned short f2bf(float f) {
    union { float f; unsigned int u; } v; v.f = f;
    unsigned int r = v.u + 0x7FFFu + ((v.u >> 16) & 1u);   // RNE
    return (unsigned short)(r >> 16);
}
// HW packed f32->bf16 (RNE) via compiler intrinsic: low16 = bf16(lo), high16 = bf16(hi)
__device__ __forceinline__ unsigned int pack2bf(float lo, float hi) {
    union { __hip_bfloat162 h; unsigned int u; } c;
    c.h = __float22bfloat162_rn(make_float2(lo, hi));
    return c.u;
}
__device__ __forceinline__ float bf2f(unsigned int bits16) {   // low 16 bits -> f32
    union { unsigned int u; float f; } v; v.u = bits16 << 16; return v.f;
}
union bfrag { unsigned int u[4]; bf16x8 v; };

// ---------------- prep_pb: Pb frags (1 block) ----------------
// Pb frag f = kstep*16+nt: B[k][n] = SCLOG2E*P[n][k], n = nt*16+(l&15), k = kstep*32+(l>>4)*8+j.
__global__ __launch_bounds__(256)
void prep_pb_kernel(const float* __restrict__ P, unsigned short* __restrict__ Pb)
{
    const int t = threadIdx.x, l = t & 63, g = t >> 6;
    for (int f = g * 8; f < g * 8 + 8; f++) {
        const int kstep = f >> 4, nt = f & 15;
        const float* src = P + (nt * 16 + (l & 15)) * 64 + kstep * 32 + (l >> 4) * 8;
        bfrag fr;
        #pragma unroll
        for (int jp = 0; jp < 4; jp++)
            fr.u[jp] = pack2bf(SCLOG2E * src[2 * jp], SCLOG2E * src[2 * jp + 1]);
        *(bf16x8*)(Pb + f * 512 + l * 8) = fr.v;
    }
}

// ---------------- A-frags + rc from registers (shared by both phi variants) ----------------
// Loads row (chunkBase + 16w + (l&15)) elements [(l>>4)*8,+8) and [32+(l>>4)*8,+8);
// builds a0,a1 bf16 frags and the per-D-reg rc four-vector via in-wave shfl reduction.
__device__ __forceinline__ void phi_afrag_rc(const float* __restrict__ X, int chunkBase,
                                             int l, int w, bfrag& a0, bfrag& a1, float4& rcv)
{
    const float4* ar = (const float4*)(X + (size_t)(chunkBase + 16 * w + (l & 15)) * 64 + (l >> 4) * 8);
    float4 x0 = ar[0], x1 = ar[1], x2 = ar[8], x3 = ar[9];
    a0.u[0] = pack2bf(x0.x, x0.y); a0.u[1] = pack2bf(x0.z, x0.w);
    a0.u[2] = pack2bf(x1.x, x1.y); a0.u[3] = pack2bf(x1.z, x1.w);
    a1.u[0] = pack2bf(x2.x, x2.y); a1.u[1] = pack2bf(x2.z, x2.w);
    a1.u[2] = pack2bf(x3.x, x3.y); a1.u[3] = pack2bf(x3.z, x3.w);
    // ssq: the 4 lane-groups with equal (l&15) hold disjoint 16-subsets of the row's 64 values
    float ssq = x0.x*x0.x + x0.y*x0.y + x0.z*x0.z + x0.w*x0.w
              + x1.x*x1.x + x1.y*x1.y + x1.z*x1.z + x1.w*x1.w
              + x2.x*x2.x + x2.y*x2.y + x2.z*x2.z + x2.w*x2.w
              + x3.x*x3.x + x3.y*x3.y + x3.z*x3.z + x3.w*x3.w;
    ssq += __shfl_xor(ssq, 16);
    ssq += __shfl_xor(ssq, 32);
    const float rcrow = RC_COEF * ssq + LOG2RATIO;     // rc of local row (l&15)
    const int r0 = 4 * (l >> 4);                       // D rows r0..r0+3
    rcv.x = __shfl(rcrow, r0 + 0);
    rcv.y = __shfl(rcrow, r0 + 1);
    rcv.z = __shfl(rcrow, r0 + 2);
    rcv.w = __shfl(rcrow, r0 + 3);
}

// ---------------- phi of a 128-row chunk -> swizzled LDS (bf16), 8 waves ----------------
// phi value for (row, feat) lands at u16 index PHI_OFF(feat, row). Ends with syncthreads.
__device__ __forceinline__ void phi_chunk8_swz(const float* __restrict__ X, int chunkBase,
                                               const unsigned short* __restrict__ Pb,
                                               unsigned short* phi_lds)
{
    const int t = threadIdx.x, l = t & 63, w = t >> 6;
    bfrag a0, a1; float4 rcv;
    phi_afrag_rc(X, chunkBase, l, w, a0, a1, rcv);
    #pragma unroll
    for (int nt = 0; nt < 16; nt++) {
        bf16x8 b0 = *(const bf16x8*)(Pb + nt * 512 + l * 8);
        bf16x8 b1 = *(const bf16x8*)(Pb + (16 + nt) * 512 + l * 8);
        f32x4 acc = (f32x4){rcv.x, rcv.y, rcv.z, rcv.w};   // C-in = rc (free add)
        acc = __builtin_amdgcn_mfma_f32_16x16x32_bf16(a0.v, b0, acc, 0, 0, 0);
        acc = __builtin_amdgcn_mfma_f32_16x16x32_bf16(a1.v, b1, acc, 0, 0, 0);
        float p0 = __builtin_amdgcn_exp2f(acc[0]);
        float p1 = __builtin_amdgcn_exp2f(acc[1]);
        float p2 = __builtin_amdgcn_exp2f(acc[2]);
        float p3 = __builtin_amdgcn_exp2f(acc[3]);
        const int col = nt * 16 + (l & 15);   // feature
        const int r0 = 16 * w + 4 * (l >> 4); // rows r0..r0+3 (bits 0..2 intact under XOR)
        unsigned int* dst = (unsigned int*)(phi_lds + PHI_OFF(col, r0));
        dst[0] = pack2bf(p0, p1);
        dst[1] = pack2bf(p2, p3);
    }
    __syncthreads();
}

// ---------------- kv: partials[blk] = phi(K)^T @ [V | 1], V staged once in LDS ----------------
__global__ __launch_bounds__(512, 4)
void kv_kernel(const float* __restrict__ Kp, const float* __restrict__ V,
               const unsigned short* __restrict__ Pb, unsigned int* __restrict__ partials)
{
    __shared__ __align__(16) unsigned short phi_lds[RFEAT * 128];   // 64 KB, swizzled
    __shared__ __align__(16) unsigned short v_lds[64 * 128];        // 16 KB, swizzled
    const int t = threadIdx.x, l = t & 63, w = t >> 6;   // w in [0,8)
    const int cb = blockIdx.x * 128;              // one 128-row chunk per block

    // T14 early-issue: thread t loads V col (t&63), krows [(t>>6)*16, +16) -> regs
    const int vcol = t & 63, vr0 = (t >> 6) * 16;
    float vreg[16];
    #pragma unroll
    for (int i = 0; i < 16; i++)
        vreg[i] = V[(size_t)(cb + vr0 + i) * 64 + vcol];

    phi_chunk8_swz(Kp, cb, Pb, phi_lds);          // ends with __syncthreads

    // convert V -> v_lds (bf16, swizzled): 2 x b128 stores per thread
    {
        unsigned int pk[8];
        #pragma unroll
        for (int i = 0; i < 8; i++) pk[i] = pack2bf(vreg[2 * i], vreg[2 * i + 1]);
        unsigned int* d0 = (unsigned int*)(v_lds + V_OFF(vcol, vr0));
        unsigned int* d1 = (unsigned int*)(v_lds + V_OFF(vcol, vr0 + 8));
        d0[0] = pk[0]; d0[1] = pk[1]; d0[2] = pk[2]; d0[3] = pk[3];
        d1[0] = pk[4]; d1[1] = pk[5]; d1[2] = pk[6]; d1[3] = pk[7];
    }
    __syncthreads();

    f32x4 acc[2][5];
    #pragma unroll
    for (int mt = 0; mt < 2; mt++)
        #pragma unroll
        for (int nt = 0; nt < 5; nt++) acc[mt][nt] = (f32x4){0.f, 0.f, 0.f, 0.f};

    bf16x8 ones;   // B-frag for ksum column: B[k][64]=1, rest 0 -> lanes with (l&15)==0
    #pragma unroll
    for (int j = 0; j < 8; j++) ones[j] = (short)(((l & 15) == 0) ? 0x3F80 : 0);

    #pragma unroll
    for (int ks = 0; ks < 4; ks++) {              // 4 k-steps of 32 krows
        const int krow0 = ks * 32 + (l >> 4) * 8;
        bf16x8 af[2];   // A = phi(K)^T: m=feature, k=krow; wave w owns feats [32w,+32)
        #pragma unroll
        for (int mt = 0; mt < 2; mt++)
            af[mt] = *(const bf16x8*)(phi_lds + PHI_OFF(32 * w + mt * 16 + (l & 15), krow0));
        bf16x8 bf4[4];  // B = V bf16 from LDS
        #pragma unroll
        for (int nt = 0; nt < 4; nt++)
            bf4[nt] = *(const bf16x8*)(v_lds + V_OFF(nt * 16 + (l & 15), krow0));
        #pragma unroll
        for (int mt = 0; mt < 2; mt++) {
            #pragma unroll
            for (int nt = 0; nt < 4; nt++)
                acc[mt][nt] = __builtin_amdgcn_mfma_f32_16x16x32_bf16(af[mt], bf4[nt], acc[mt][nt], 0, 0, 0);
            acc[mt][4] = __builtin_amdgcn_mfma_f32_16x16x32_bf16(af[mt], ones, acc[mt][4], 0, 0, 0);
        }
    }
    // partials slot: u32 word at [featpair][col], featpair = feat>>1, stride PCOL
    unsigned int* slot = partials + (size_t)blockIdx.x * PARTU;
    #pragma unroll
    for (int mt = 0; mt < 2; mt++) {
        const int fpb = 16 * w + mt * 8 + ((l >> 4) << 1);   // feat-pair row of regs 0,1
        #pragma unroll
        for (int nt = 0; nt < 5; nt++) {
            if (nt == 4 && (l & 15) != 0) continue;
            const int col = nt * 16 + (l & 15);              // nt==4 -> col 64 (ksum)
            slot[fpb * PCOL + col]       = pack2bf(acc[mt][nt][0], acc[mt][nt][1]);
            slot[(fpb + 1) * PCOL + col] = pack2bf(acc[mt][nt][2], acc[mt][nt][3]);
        }
    }
}

// ---------------- reduceA: sum 64 slots (bf16 pairs, f32 accum) -> p2[g][8448] float2 ----------------
__global__ __launch_bounds__(256)
void reduceA_kernel(const unsigned int* __restrict__ partials, float2* __restrict__ p2)
{
    const int idx = blockIdx.x * 256 + threadIdx.x;   // 33*256 == 8448 exactly
    const int g = blockIdx.y;
    const unsigned int* base = partials + (size_t)g * 64 * PARTU + idx;
    float lo0 = 0.f, hi0 = 0.f, lo1 = 0.f, hi1 = 0.f;
    #pragma unroll 4
    for (int s = 0; s < 64; s += 2) {
        unsigned int u0 = base[(size_t)s * PARTU];
        unsigned int u1 = base[(size_t)(s + 1) * PARTU];
        lo0 += bf2f(u0 & 0xFFFFu); hi0 += bf2f(u0 >> 16);
        lo1 += bf2f(u1 & 0xFFFFu); hi1 += bf2f(u1 >> 16);
    }
    p2[(size_t)g * PARTU + idx] = make_float2(lo0 + lo1, hi0 + hi1);
}

// ---------------- reduceB: sum groups -> Zb (bf16, B-frag octet layout) ----------------
// Zb element (m,n) at ushort ((m>>3)*80 + n)*8 + (m&7); col 64 = ksum.
__global__ __launch_bounds__(256)
void reduceB_kernel(const float2* __restrict__ p2, unsigned short* __restrict__ Zb)
{
    const int idx = blockIdx.x * 256 + threadIdx.x;   // 0..8447
    float sLo = 0.f, sHi = 0.f;
    #pragma unroll
    for (int g = 0; g < NGRP; g++) {
        float2 v = p2[(size_t)g * PARTU + idx];
        sLo += v.x; sHi += v.y;
    }
    const int fp = idx / PCOL, col = idx - fp * PCOL;
    if (col >= 65) return;               // pad col
    const int m0 = 2 * fp, m1 = m0 + 1;
    Zb[((m0 >> 3) * 80 + col) * 8 + (m0 & 7)] = f2bf(sLo);
    Zb[((m1 >> 3) * 80 + col) * 8 + (m1 & 7)] = f2bf(sHi);
}

// ---------------- phi of a 64-row chunk -> LDS [row][feat] (4 waves, for q_out) ----------------
__device__ __forceinline__ void phi_chunk_q(const float* __restrict__ X, int chunkBase,
                                            const unsigned short* __restrict__ Pb,
                                            unsigned short* phi_lds)
{
    const int t = threadIdx.x, l = t & 63, w = t >> 6;
    bfrag a0, a1; float4 rcv;
    phi_afrag_rc(X, chunkBase, l, w, a0, a1, rcv);
    #pragma unroll
    for (int nt = 0; nt < 16; nt++) {
        bf16x8 b0 = *(const bf16x8*)(Pb + nt * 512 + l * 8);
        bf16x8 b1 = *(const bf16x8*)(Pb + (16 + nt) * 512 + l * 8);
        f32x4 acc = (f32x4){rcv.x, rcv.y, rcv.z, rcv.w};
        acc = __builtin_amdgcn_mfma_f32_16x16x32_bf16(a0.v, b0, acc, 0, 0, 0);
        acc = __builtin_amdgcn_mfma_f32_16x16x32_bf16(a1.v, b1, acc, 0, 0, 0);
        float p0 = __builtin_amdgcn_exp2f(acc[0]);
        float p1 = __builtin_amdgcn_exp2f(acc[1]);
        float p2 = __builtin_amdgcn_exp2f(acc[2]);
        float p3 = __builtin_amdgcn_exp2f(acc[3]);
        const int col = nt * 16 + (l & 15);
        unsigned int w0 = pack2bf(p0, p1);
        unsigned int w1 = pack2bf(p2, p3);
        const int rb = (16 * w + (l >> 4) * 4) * LDQ + col;
        phi_lds[rb]           = (unsigned short)(w0);
        phi_lds[rb + LDQ]     = (unsigned short)(w0 >> 16);
        phi_lds[rb + 2 * LDQ] = (unsigned short)(w1);
        phi_lds[rb + 3 * LDQ] = (unsigned short)(w1 >> 16);
    }
    __syncthreads();
}

// ---------------- q_out: out = normalize( phi(Q) @ Zb ) ----------------
__global__ __launch_bounds__(256, 4)
void q_out_kernel(const float* __restrict__ Q, const unsigned short* __restrict__ Pb,
                  const unsigned short* __restrict__ Zb, float* __restrict__ out)
{
    __shared__ __align__(16) unsigned short phi_lds[64 * LDQ];   // [row][feat], padded
    const int t = threadIdx.x, l = t & 63, w = t >> 6;
    const int base = blockIdx.x * 64;

    phi_chunk_q(Q, base, Pb, phi_lds);

    f32x4 acc[5];
    #pragma unroll
    for (int nt = 0; nt < 5; nt++) acc[nt] = (f32x4){0.f, 0.f, 0.f, 0.f};

    #pragma unroll
    for (int ks = 0; ks < 8; ks++) {
        // A = phi(Q): m = qrow (wave w rows 16w..+16), k = feature
        bf16x8 a = *(const bf16x8*)(phi_lds + (16 * w + (l & 15)) * LDQ + ks * 32 + (l >> 4) * 8);
        #pragma unroll
        for (int nt = 0; nt < 5; nt++) {
            bf16x8 b = *(const bf16x8*)(Zb + ((ks * 4 + (l >> 4)) * 80 + nt * 16 + (l & 15)) * 8);
            acc[nt] = __builtin_amdgcn_mfma_f32_16x16x32_bf16(a, b, acc[nt], 0, 0, 0);
        }
    }
    // denom = output column 64 -> tile 4, lanes with (l&15)==0; broadcast within 16-group
    float inv[4];
    #pragma unroll
    for (int reg = 0; reg < 4; reg++) {
        float den = __shfl(acc[4][reg], (l & 48));
        inv[reg] = 1.0f / den;
    }
    const int row = base + 16 * w + (l >> 4) * 4;
    #pragma unroll
    for (int nt = 0; nt < 4; nt++)
        #pragma unroll
        for (int reg = 0; reg < 4; reg++)
            out[(size_t)(row + reg) * 64 + nt * 16 + (l & 15)] = acc[nt][reg] * inv[reg];
}

extern "C" void kernel_launch(void* const* d_in, const int* in_sizes, int n_in,
                              void* d_out, int out_size, void* d_ws, size_t ws_size,
                              hipStream_t stream) {
    const float* q = (const float*)d_in[0];
    const float* k = (const float*)d_in[1];
    const float* v = (const float*)d_in[2];
    const float* P = (const float*)d_in[3];
    float* out = (float*)d_out;

    unsigned short* Pb = (unsigned short*)d_ws;                      // 32 frags = 32KB
    unsigned short* Zb = Pb + 32 * 512;                              // 20480 u16 = 40KB
    float2* p2 = (float2*)((char*)d_ws + 73728);                     // 8*8448*8 = 540.7KB
    unsigned int* partials = (unsigned int*)((char*)d_ws + 73728 + 540672); // 512*8448*4 = 17.3MB

    prep_pb_kernel<<<1, 256, 0, stream>>>(P, Pb);
    kv_kernel<<<NBKV, 512, 0, stream>>>(k, v, Pb, partials);
    reduceA_kernel<<<dim3(33, NGRP), 256, 0, stream>>>(partials, p2);
    reduceB_kernel<<<33, 256, 0, stream>>>(p2, Zb);
    q_out_kernel<<<1024, 256, 0, stream>>>(q, Pb, Zb, out);
}